// Round 16
// baseline (193.371 us; speedup 1.0000x reference)
//
#include <hip/hip_runtime.h>
#include <hip/hip_bf16.h>

#define TOTAL_N   131072
#define NEDGE     4194304
#define NPG       2048
#define IN_DIM_K  128
#define HID_K     256
#define EMB_K     64
#define NAGENT    64

#define F1CAP     4096
#define APACK     128        // per-agent e0 slot cap
#define BCAP      96         // per-F1-node edge bucket cap (mean 32, P(>96)~1e-18)

#define G1        256                 // edge-scan blocks
#define EPB1      (NEDGE / G1)        // 16384 edges per block

// ---------------- workspace layout (bytes) ----------------
// zeroed every launch [0, 574592):
//   0        counters  int[256]        ([1]=nF1)
//   1024     inF1      int[F1CAP]      16K
//   17408    e0cnt     int[64]         256B
//   17664    bitmap    u32[4096]       16K   (F1 membership)
//   34048    bitmap2   u32[4096]       16K   (F2 membership: distinct E1 srcs)
//   50304    out_deg   u32[TOTAL_N]    512K  (counted only for F1 ∪ F2)
// not zeroed (fully written before read):
//   589824   loc       int[TOTAL_N]    512K
//   1114112  e0pack    int[64*APACK]   32K
//   1146880  es_bucket int[F1CAP*BCAP] 1.5M
//   2719744  wswz      u16[32768]      64K
//   2785280  h1        f32[F1CAP*HID]  4M
//   6979584  agg1      f32[F1CAP*HID]  4M
// total ~11.2 MB

#define ZERO_SPAN 574592

typedef float f32x4 __attribute__((ext_vector_type(4)));
typedef short bf16x8 __attribute__((ext_vector_type(8)));

__device__ inline unsigned short f2bf(float f) {   // RNE f32->bf16
    unsigned int u = __float_as_uint(f);
    return (unsigned short)((u + 0x7FFFu + ((u >> 16) & 1u)) >> 16);
}

// K1: pure dst stream — F1 bitmap marking + e0 bucket select. No histogram.
__global__ __launch_bounds__(1024) void k_dst_scan(
    const int* __restrict__ src, const int* __restrict__ dst,
    unsigned int* __restrict__ bitmap,
    int* __restrict__ e0pack, int* __restrict__ e0cnt)
{
    int t = threadIdx.x;
    int ebase = blockIdx.x * EPB1;
    const int4* d4 = (const int4*)(dst + ebase);
    #pragma unroll
    for (int i = 0; i < EPB1 / 4096; i++) {     // 4 iterations
        int4 dv = d4[i * 1024 + t];
        int eidx = ebase + (i * 1024 + t) * 4;
        int dd[4] = {dv.x, dv.y, dv.z, dv.w};
        #pragma unroll
        for (int j = 0; j < 4; j++) {
            int d = dd[j];
            if ((d & (NPG - 1)) == 0) {
                int s = src[eidx + j];               // sparse (~2K total)
                atomicOr(&bitmap[s >> 5], 1u << (s & 31));
                int a = d >> 11;
                int slot = atomicAdd(&e0cnt[a], 1);
                if (slot < APACK) e0pack[a * APACK + slot] = s;
            }
        }
    }
}

// K2 (aux, 132 blocks x 1024): [0,128) compact F1 from bitmap | [128,132) wprep
__global__ __launch_bounds__(1024) void k_aux(
    const unsigned int* __restrict__ bitmap, int* __restrict__ loc,
    int* __restrict__ counters,
    const float* __restrict__ wlin, unsigned short* __restrict__ wswz)
{
    int b = blockIdx.x;
    int t = threadIdx.x;
    if (b < 128) {
        __shared__ int cnt, gbase;
        if (t == 0) cnt = 0;
        __syncthreads();
        int v = b * 1024 + t;
        int f = (bitmap[v >> 5] >> (v & 31)) & 1u;
        int p = -1;
        if (f) p = atomicAdd(&cnt, 1);
        __syncthreads();
        if (t == 0) gbase = cnt ? atomicAdd(&counters[1], cnt) : 0;
        __syncthreads();
        int l = -1;
        if (p >= 0) { int id = gbase + p; if (id < F1CAP) l = id; }
        loc[v] = l;
    } else {
        int g = (b - 128) * 1024 + t;            // 4096 items
        int lane = g & 63, ct = (g >> 6) & 15, kt = g >> 10;
        int colbase = ct * 16 + (lane & 15);
        int kbase = kt * 32 + (lane >> 4) * 8;
        unsigned short o[8];
        #pragma unroll
        for (int i = 0; i < 8; i++) o[i] = f2bf(wlin[(kbase + i) * HID_K + colbase]);
        *(ushort4*)(wswz + g * 8)     = make_ushort4(o[0], o[1], o[2], o[3]);
        *(ushort4*)(wswz + g * 8 + 4) = make_ushort4(o[4], o[5], o[6], o[7]);
    }
}

// K3: select edges with dst in F1 — bucket scatter + F2 marking.
// Slot atomic doubles as the inF1 in-degree count.
__global__ __launch_bounds__(1024) void k_e1_select(
    const int* __restrict__ src, const int* __restrict__ dst,
    const int* __restrict__ loc, const unsigned int* __restrict__ bitmap,
    int* __restrict__ inF1, int* __restrict__ es_bucket,
    unsigned int* __restrict__ bitmap2)
{
    __shared__ unsigned int bm[TOTAL_N / 32];   // 16 KB
    int t = threadIdx.x;
    ((uint4*)bm)[t] = ((const uint4*)bitmap)[t];
    __syncthreads();

    int ebase = blockIdx.x * EPB1;
    const int4* d4p = (const int4*)(dst + ebase);
    #pragma unroll
    for (int i = 0; i < EPB1 / 4096; i++) {     // 4 iterations
        int4 d4 = d4p[i * 1024 + t];
        int eidx = ebase + (i * 1024 + t) * 4;
        int dd[4] = {d4.x, d4.y, d4.z, d4.w};
        #pragma unroll
        for (int j = 0; j < 4; j++) {
            int d = dd[j];
            if ((bm[d >> 5] >> (d & 31)) & 1u) {
                int l = loc[d];
                if (l >= 0) {
                    int s = src[eidx + j];
                    atomicOr(&bitmap2[s >> 5], 1u << (s & 31));
                    int slot = atomicAdd(&inF1[l], 1);
                    if (slot < BCAP) es_bucket[l * BCAP + slot] = s;
                }
            }
        }
    }
}

// K3b: src stream — out-degree count ONLY for F1 ∪ F2 members (~1.7M atomics
// into L2-resident 512K array; bitmaps staged in 32 KB LDS)
__global__ __launch_bounds__(1024) void k_deg(
    const int* __restrict__ src,
    const unsigned int* __restrict__ bitmap, const unsigned int* __restrict__ bitmap2,
    unsigned int* __restrict__ out_deg)
{
    __shared__ unsigned int bm[TOTAL_N / 32];    // 16 KB (F1)
    __shared__ unsigned int bm2[TOTAL_N / 32];   // 16 KB (F2)
    int t = threadIdx.x;
    ((uint4*)bm)[t]  = ((const uint4*)bitmap)[t];
    ((uint4*)bm2)[t] = ((const uint4*)bitmap2)[t];
    __syncthreads();

    int ebase = blockIdx.x * EPB1;
    const int4* s4 = (const int4*)(src + ebase);
    #pragma unroll
    for (int i = 0; i < EPB1 / 4096; i++) {     // 4 iterations
        int4 sv = s4[i * 1024 + t];
        int ss[4] = {sv.x, sv.y, sv.z, sv.w};
        #pragma unroll
        for (int j = 0; j < 4; j++) {
            int s = ss[j];
            if (((bm[s >> 5] | bm2[s >> 5]) >> (s & 31)) & 1u)
                atomicAdd(&out_deg[s], 1u);
        }
    }
}

// K4: per-F1-node MFMA edge-GEMM (r14-proven verbatim). Batch gather of all
// tiles barrier-free, then MFMA from LDS, shuffle row-sum, plain store.
__global__ __launch_bounds__(256) void k_h0agg(
    const float* __restrict__ x, const unsigned short* __restrict__ wswz,
    const float* __restrict__ blin, const int* __restrict__ es_bucket,
    const unsigned int* __restrict__ out_deg, const int* __restrict__ inF1,
    const int* __restrict__ counters, float* __restrict__ agg1)
{
    __shared__ unsigned short A[3 * 32][136];   // 25.5 KB: up to 96 bf16 rows
    __shared__ float escs[3 * 32];
    __shared__ int rsrc[3 * 32];

    int nF1 = min(counters[1], F1CAP);
    int l = blockIdx.x;
    if (l >= nF1) return;
    int cnt = min(inF1[l], BCAP);
    int ntile = (cnt + 31) >> 5;            // 0..3
    int t = threadIdx.x;
    int lane = t & 63, wq = t >> 6;
    int cbase = lane & 15, rgrp = (lane >> 4) * 4;

    if (t < 96) {
        int s = (t < cnt) ? es_bucket[l * BCAP + t] : -1;
        rsrc[t] = s;
        escs[t] = (s >= 0) ? rsqrtf((float)max((int)out_deg[s], 1)) : 0.f;
    }
    __syncthreads();

    int nslots = (ntile * 32) * 32;
    for (int idx = t; idx < nslots; idx += 256) {
        int r = idx >> 5, q = idx & 31;
        int s = rsrc[r];
        float4 v = make_float4(0.f, 0.f, 0.f, 0.f);
        if (s >= 0) v = ((const float4*)(x + (long long)s * IN_DIM_K))[q];
        ushort4 h;
        h.x = f2bf(v.x); h.y = f2bf(v.y); h.z = f2bf(v.z); h.w = f2bf(v.w);
        *(ushort4*)&A[r][q * 4] = h;
    }
    __syncthreads();

    float bj[4];
    #pragma unroll
    for (int n = 0; n < 4; n++) bj[n] = blin[wq * 64 + n * 16 + cbase];

    float colacc[4] = {0.f, 0.f, 0.f, 0.f};

    for (int ti = 0; ti < ntile; ti++) {
        f32x4 acc[2][4];
        #pragma unroll
        for (int m = 0; m < 2; m++)
            #pragma unroll
            for (int n = 0; n < 4; n++) acc[m][n] = (f32x4){0.f, 0.f, 0.f, 0.f};

        const unsigned short* Ab = &A[ti * 32][0];
        #pragma unroll
        for (int kt = 0; kt < 4; kt++) {
            bf16x8 a0 = *(const bf16x8*)(Ab + ((lane & 15) * 136 + kt * 32 + (lane >> 4) * 8));
            bf16x8 a1 = *(const bf16x8*)(Ab + (((lane & 15) + 16) * 136 + kt * 32 + (lane >> 4) * 8));
            #pragma unroll
            for (int n = 0; n < 4; n++) {
                bf16x8 bf = *(const bf16x8*)(wswz + ((kt * 16 + wq * 4 + n) * 64 + lane) * 8);
                acc[0][n] = __builtin_amdgcn_mfma_f32_16x16x32_bf16(a0, bf, acc[0][n], 0, 0, 0);
                acc[1][n] = __builtin_amdgcn_mfma_f32_16x16x32_bf16(a1, bf, acc[1][n], 0, 0, 0);
            }
        }

        #pragma unroll
        for (int n = 0; n < 4; n++) {
            float part = 0.f;
            #pragma unroll
            for (int m = 0; m < 2; m++)
                #pragma unroll
                for (int j = 0; j < 4; j++) {
                    int row = m * 16 + rgrp + j;
                    part += fmaxf(acc[m][n][j] + bj[n], 0.f) * escs[ti * 32 + row];
                }
            part += __shfl_xor(part, 16);
            part += __shfl_xor(part, 32);
            colacc[n] += part;
        }
    }

    if (lane < 16) {
        #pragma unroll
        for (int n = 0; n < 4; n++)
            agg1[(long long)l * HID_K + wq * 64 + n * 16 + lane] = colacc[n];
    }
}

// K5: h1[l] = relu((agg1[l]*in_norm)@w_c0 + b_c0)  (proven verbatim)
__global__ __launch_bounds__(256) void k_h1(
    const float* __restrict__ agg1, const float* __restrict__ wc0,
    const float* __restrict__ bc0,
    const int* __restrict__ inF1,
    const int* __restrict__ counters, float* __restrict__ h1)
{
    __shared__ float as[16][HID_K];
    __shared__ float ns[16];

    int nF1 = min(counters[1], F1CAP);
    int base = blockIdx.x * 16;
    if (base >= nF1) return;
    int t = threadIdx.x;

    if (t < 16) {
        int l = base + t;
        ns[t] = (l < nF1) ? rsqrtf((float)max(inF1[l], 1)) : 0.f;
    }
    __syncthreads();

    #pragma unroll
    for (int i = 0; i < 4; i++) {
        int idx = t + i * 256;
        int e = idx >> 6;
        int q = idx & 63;
        int l = base + e;
        float4 v = make_float4(0.f, 0.f, 0.f, 0.f);
        if (l < nF1) v = ((const float4*)(agg1 + (long long)l * HID_K))[q];
        float sc = ns[e];
        v.x *= sc; v.y *= sc; v.z *= sc; v.w *= sc;
        ((float4*)as[e])[q] = v;
    }
    __syncthreads();

    float acc[16];
    #pragma unroll
    for (int e = 0; e < 16; e++) acc[e] = 0.f;

    int j = t;
    for (int k = 0; k < HID_K; k += 4) {
        float w0 = wc0[(k + 0) * HID_K + j];
        float w1 = wc0[(k + 1) * HID_K + j];
        float w2 = wc0[(k + 2) * HID_K + j];
        float w3 = wc0[(k + 3) * HID_K + j];
        #pragma unroll
        for (int e = 0; e < 16; e++) {
            float4 av = *(const float4*)&as[e][k];
            acc[e] = fmaf(av.x, w0, acc[e]);
            acc[e] = fmaf(av.y, w1, acc[e]);
            acc[e] = fmaf(av.z, w2, acc[e]);
            acc[e] = fmaf(av.w, w3, acc[e]);
        }
    }

    float bj = bc0[j];
    #pragma unroll
    for (int e = 0; e < 16; e++) {
        int l = base + e;
        if (l < nF1) h1[(long long)l * HID_K + j] = fmaxf(acc[e] + bj, 0.f);
    }
}

// K6: per agent: gather e0 list, aggregate h1, 2 GEMMs (proven verbatim)
__global__ __launch_bounds__(256) void k_final(
    const int* __restrict__ e0pack, const int* __restrict__ e0cnt,
    const int* __restrict__ loc, const unsigned int* __restrict__ out_deg,
    const float* __restrict__ h1,
    const float* __restrict__ wc1, const float* __restrict__ bc1,
    const float* __restrict__ wemb, const float* __restrict__ bemb,
    float* __restrict__ out)
{
    __shared__ float a_s[HID_K];
    __shared__ float h2[HID_K];
    __shared__ int   ls[APACK];
    __shared__ float scs[APACK];
    int a = blockIdx.x;
    int t = threadIdx.x;

    int n0 = e0cnt[a];
    int ne = min(n0, APACK);
    if (t < ne) {
        int s = e0pack[a * APACK + t];
        int l = loc[s];
        ls[t] = l;
        scs[t] = (l >= 0) ? rsqrtf((float)max((int)out_deg[s], 1)) : 0.f;
    }
    __syncthreads();

    float acc = 0.f;
    for (int i = 0; i < ne; i++) {
        int l = ls[i];
        if (l >= 0) acc = fmaf(scs[i], h1[(long long)l * HID_K + t], acc);
    }
    a_s[t] = acc * rsqrtf((float)max(n0, 1));
    __syncthreads();

    float h = 0.f;
    for (int k = 0; k < HID_K; k++)
        h = fmaf(a_s[k], wc1[k * HID_K + t], h);
    h2[t] = fmaxf(h + bc1[t], 0.f);
    __syncthreads();

    if (t < EMB_K) {
        float o = bemb[t];
        for (int k = 0; k < HID_K; k++)
            o = fmaf(h2[k], wemb[k * EMB_K + t], o);
        out[a * EMB_K + t] = o;
    }
}

extern "C" void kernel_launch(void* const* d_in, const int* in_sizes, int n_in,
                              void* d_out, int out_size, void* d_ws, size_t ws_size,
                              hipStream_t stream)
{
    const float* x    = (const float*)d_in[0];
    const int*   src  = (const int*)d_in[1];
    const int*   dst  = (const int*)d_in[2];
    const float* wlin = (const float*)d_in[5];
    const float* blin = (const float*)d_in[6];
    const float* wc0  = (const float*)d_in[7];
    const float* bc0  = (const float*)d_in[8];
    const float* wc1  = (const float*)d_in[9];
    const float* bc1  = (const float*)d_in[10];
    const float* wemb = (const float*)d_in[11];
    const float* bemb = (const float*)d_in[12];
    float* out = (float*)d_out;

    char* ws = (char*)d_ws;
    int*            counters  = (int*)(ws + 0);
    int*            inF1      = (int*)(ws + 1024);
    int*            e0cnt     = (int*)(ws + 17408);
    unsigned int*   bitmap    = (unsigned int*)(ws + 17664);
    unsigned int*   bitmap2   = (unsigned int*)(ws + 34048);
    unsigned int*   out_deg   = (unsigned int*)(ws + 50304);
    int*            loc       = (int*)(ws + 589824);
    int*            e0pack    = (int*)(ws + 1114112);
    int*            es_bucket = (int*)(ws + 1146880);
    unsigned short* wswz      = (unsigned short*)(ws + 2719744);
    float*          h1        = (float*)(ws + 2785280);
    float*          agg1      = (float*)(ws + 6979584);

    hipMemsetAsync(ws, 0, ZERO_SPAN, stream);

    k_dst_scan<<<G1, 1024, 0, stream>>>(src, dst, bitmap, e0pack, e0cnt);
    k_aux<<<132, 1024, 0, stream>>>(bitmap, loc, counters, wlin, wswz);
    k_e1_select<<<G1, 1024, 0, stream>>>(src, dst, loc, bitmap,
                                         inF1, es_bucket, bitmap2);
    k_deg<<<G1, 1024, 0, stream>>>(src, bitmap, bitmap2, out_deg);
    k_h0agg<<<F1CAP, 256, 0, stream>>>(x, wswz, blin, es_bucket, out_deg,
                                       inF1, counters, agg1);
    k_h1<<<F1CAP / 16, 256, 0, stream>>>(agg1, wc0, bc0, inF1, counters, h1);
    k_final<<<NAGENT, 256, 0, stream>>>(e0pack, e0cnt, loc, out_deg, h1,
                                        wc1, bc1, wemb, bemb, out);
}

// Round 17
// 116.648 us; speedup vs baseline: 1.6577x; 1.6577x over previous
//
#include <hip/hip_runtime.h>
#include <hip/hip_bf16.h>

#define TOTAL_N   131072
#define NEDGE     4194304
#define NPG       2048
#define IN_DIM_K  128
#define HID_K     256
#define EMB_K     64
#define NAGENT    64

#define F1CAP     4096
#define APACK     128        // per-agent e0 slot cap
#define BCAP      96         // per-F1-node edge bucket cap (mean 32, P(>96)~1e-18)

#define G1        256                 // k_outdeg_e0 blocks
#define EPB1      (NEDGE / G1)        // 16384 edges per block
#define HWORDS    (TOTAL_N / 8)       // 16384 nibble-packed u32 words

#define SELB      256                 // k_e1_select blocks (persistent)
#define EPB       (NEDGE / SELB)      // 16384 edges per block

// ---------------- workspace layout (bytes) ----------------
// zeroed every launch [0, 34048):
//   0        counters  int[256]        ([1]=nF1)
//   1024     inF1      int[F1CAP]      16K
//   17408    e0cnt     int[64]         256B
//   17664    bitmap    u32[4096]       16K
// not zeroed (fully written before read):
//   65536    loc       int[TOTAL_N]    512K
//   589824   e0pack    int[64*APACK]   32K
//   622592   es_bucket int[F1CAP*BCAP] 1.5M
//   2195456  out_deg   u32[TOTAL_N]    512K
//   2719744  wswz      u16[32768]      64K
//   2785280  h1        f32[F1CAP*HID]  4M
//   6979584  agg1      f32[F1CAP*HID]  4M    (rows l<nF1 plain-stored by h0agg)
//   11173888 partial   u32[G1*HWORDS]  16M
// total ~26.7 MB

#define ZERO_SPAN 34048

typedef float f32x4 __attribute__((ext_vector_type(4)));
typedef short bf16x8 __attribute__((ext_vector_type(8)));

__device__ inline unsigned short f2bf(float f) {   // RNE f32->bf16
    unsigned int u = __float_as_uint(f);
    return (unsigned short)((u + 0x7FFFu + ((u >> 16) & 1u)) >> 16);
}

// K1: out-degree nibble histogram + e0 select + F1 bitmap marking
__global__ __launch_bounds__(1024) void k_outdeg_e0(
    const int* __restrict__ src, const int* __restrict__ dst,
    unsigned int* __restrict__ partial,
    unsigned int* __restrict__ bitmap,
    int* __restrict__ e0pack, int* __restrict__ e0cnt)
{
    __shared__ unsigned int hist[HWORDS];   // 64 KB
    int t = threadIdx.x;
    #pragma unroll
    for (int i = 0; i < HWORDS / 1024; i++) hist[t + i * 1024] = 0u;
    __syncthreads();

    int ebase = blockIdx.x * EPB1;
    const int4* s4 = (const int4*)(src + ebase);
    const int4* d4 = (const int4*)(dst + ebase);
    #pragma unroll
    for (int i = 0; i < EPB1 / 4096; i++) {     // 4 iterations
        int4 sv = s4[i * 1024 + t];
        int4 dv = d4[i * 1024 + t];
        int ss[4] = {sv.x, sv.y, sv.z, sv.w};
        int dd[4] = {dv.x, dv.y, dv.z, dv.w};
        #pragma unroll
        for (int j = 0; j < 4; j++) {
            int s = ss[j], d = dd[j];
            atomicAdd(&hist[s >> 3], 1u << ((s & 7) * 4));
            if ((d & (NPG - 1)) == 0) {
                atomicOr(&bitmap[s >> 5], 1u << (s & 31));
                int a = d >> 11;
                int slot = atomicAdd(&e0cnt[a], 1);
                if (slot < APACK) e0pack[a * APACK + slot] = s;
            }
        }
    }
    __syncthreads();
    unsigned int* pout = partial + blockIdx.x * HWORDS;
    #pragma unroll
    for (int i = 0; i < HWORDS / 1024; i++) pout[t + i * 1024] = hist[t + i * 1024];
}

// K2 (merged aux+reduce, 260 blocks x 1024):
//   [0,128) compact | [128,256) out_deg reduce | [256,260) wprep
__global__ __launch_bounds__(1024) void k_auxred(
    const unsigned int* __restrict__ bitmap, int* __restrict__ loc,
    int* __restrict__ counters,
    const unsigned int* __restrict__ partial, unsigned int* __restrict__ out_deg,
    const float* __restrict__ wlin, unsigned short* __restrict__ wswz)
{
    int b = blockIdx.x;
    int t = threadIdx.x;
    if (b < 128) {
        __shared__ int cnt, gbase;
        if (t == 0) cnt = 0;
        __syncthreads();
        int v = b * 1024 + t;
        int f = (bitmap[v >> 5] >> (v & 31)) & 1u;
        int p = -1;
        if (f) p = atomicAdd(&cnt, 1);
        __syncthreads();
        if (t == 0) gbase = cnt ? atomicAdd(&counters[1], cnt) : 0;
        __syncthreads();
        int l = -1;
        if (p >= 0) { int id = gbase + p; if (id < F1CAP) l = id; }
        loc[v] = l;
    } else if (b < 256) {
        __shared__ unsigned int redE[8][128], redO[8][128];   // 8 KB
        int wl = t & 127, gs = t >> 7;
        int w = (b - 128) * 128 + wl;
        unsigned int accE = 0, accO = 0;
        #pragma unroll 8
        for (int i = 0; i < 32; i++) {
            unsigned int v = partial[(gs * 32 + i) * HWORDS + w];
            accE += v & 0x0F0F0F0Fu;
            accO += (v >> 4) & 0x0F0F0F0Fu;
        }
        redE[gs][wl] = accE;
        redO[gs][wl] = accO;
        __syncthreads();
        if (gs == 0) {
            unsigned int sE = 0, sO = 0;
            #pragma unroll
            for (int j = 0; j < 8; j++) { sE += redE[j][wl]; sO += redO[j][wl]; }
            uint4 lo = make_uint4(sE & 255u, sO & 255u, (sE >> 8) & 255u, (sO >> 8) & 255u);
            uint4 hi = make_uint4((sE >> 16) & 255u, (sO >> 16) & 255u, (sE >> 24) & 255u, (sO >> 24) & 255u);
            ((uint4*)(out_deg + 8 * w))[0] = lo;
            ((uint4*)(out_deg + 8 * w))[1] = hi;
        }
    } else {
        int g = (b - 256) * 1024 + t;            // 4096 items
        int lane = g & 63, ct = (g >> 6) & 15, kt = g >> 10;
        int colbase = ct * 16 + (lane & 15);
        int kbase = kt * 32 + (lane >> 4) * 8;
        unsigned short o[8];
        #pragma unroll
        for (int i = 0; i < 8; i++) o[i] = f2bf(wlin[(kbase + i) * HID_K + colbase]);
        *(ushort4*)(wswz + g * 8)     = make_ushort4(o[0], o[1], o[2], o[3]);
        *(ushort4*)(wswz + g * 8 + 4) = make_ushort4(o[4], o[5], o[6], o[7]);
    }
}

// K3: select edges with dst in F1 — direct bucket scatter; slot atomic doubles
// as the inF1 in-degree count.
__global__ __launch_bounds__(1024) void k_e1_select(
    const int* __restrict__ src, const int* __restrict__ dst,
    const int* __restrict__ loc, const unsigned int* __restrict__ bitmap,
    int* __restrict__ inF1, int* __restrict__ es_bucket)
{
    __shared__ unsigned int bm[TOTAL_N / 32];   // 16 KB
    int t = threadIdx.x;
    ((uint4*)bm)[t] = ((const uint4*)bitmap)[t];
    __syncthreads();

    int ebase = blockIdx.x * EPB;
    const int4* d4p = (const int4*)(dst + ebase);
    #pragma unroll
    for (int i = 0; i < EPB / 4096; i++) {      // 4 iterations
        int4 d4 = d4p[i * 1024 + t];
        int eidx = ebase + (i * 1024 + t) * 4;
        int dd[4] = {d4.x, d4.y, d4.z, d4.w};
        #pragma unroll
        for (int j = 0; j < 4; j++) {
            int d = dd[j];
            if ((bm[d >> 5] >> (d & 31)) & 1u) {
                int l = loc[d];
                if (l >= 0) {
                    int slot = atomicAdd(&inF1[l], 1);
                    if (slot < BCAP) es_bucket[l * BCAP + slot] = src[eidx + j];
                }
            }
        }
    }
}

// K4: per-F1-node MFMA edge-GEMM. Batch gather of ALL tiles in one barrier-free
// loop, then MFMA from LDS, shuffle row-sum, plain store. 2 barriers total.
__global__ __launch_bounds__(256) void k_h0agg(
    const float* __restrict__ x, const unsigned short* __restrict__ wswz,
    const float* __restrict__ blin, const int* __restrict__ es_bucket,
    const unsigned int* __restrict__ out_deg, const int* __restrict__ inF1,
    const int* __restrict__ counters, float* __restrict__ agg1)
{
    __shared__ unsigned short A[3 * 32][136];   // 25.5 KB: up to 96 bf16 rows
    __shared__ float escs[3 * 32];
    __shared__ int rsrc[3 * 32];

    int nF1 = min(counters[1], F1CAP);
    int l = blockIdx.x;
    if (l >= nF1) return;
    int cnt = min(inF1[l], BCAP);
    int ntile = (cnt + 31) >> 5;            // 0..3
    int t = threadIdx.x;
    int lane = t & 63, wq = t >> 6;
    int cbase = lane & 15, rgrp = (lane >> 4) * 4;

    if (t < 96) {
        int s = (t < cnt) ? es_bucket[l * BCAP + t] : -1;
        rsrc[t] = s;
        escs[t] = (s >= 0) ? rsqrtf((float)max((int)out_deg[s], 1)) : 0.f;
    }
    __syncthreads();

    int nslots = (ntile * 32) * 32;
    for (int idx = t; idx < nslots; idx += 256) {
        int r = idx >> 5, q = idx & 31;
        int s = rsrc[r];
        float4 v = make_float4(0.f, 0.f, 0.f, 0.f);
        if (s >= 0) v = ((const float4*)(x + (long long)s * IN_DIM_K))[q];
        ushort4 h;
        h.x = f2bf(v.x); h.y = f2bf(v.y); h.z = f2bf(v.z); h.w = f2bf(v.w);
        *(ushort4*)&A[r][q * 4] = h;
    }
    __syncthreads();

    float bj[4];
    #pragma unroll
    for (int n = 0; n < 4; n++) bj[n] = blin[wq * 64 + n * 16 + cbase];

    float colacc[4] = {0.f, 0.f, 0.f, 0.f};

    for (int ti = 0; ti < ntile; ti++) {
        f32x4 acc[2][4];
        #pragma unroll
        for (int m = 0; m < 2; m++)
            #pragma unroll
            for (int n = 0; n < 4; n++) acc[m][n] = (f32x4){0.f, 0.f, 0.f, 0.f};

        const unsigned short* Ab = &A[ti * 32][0];
        #pragma unroll
        for (int kt = 0; kt < 4; kt++) {
            bf16x8 a0 = *(const bf16x8*)(Ab + ((lane & 15) * 136 + kt * 32 + (lane >> 4) * 8));
            bf16x8 a1 = *(const bf16x8*)(Ab + (((lane & 15) + 16) * 136 + kt * 32 + (lane >> 4) * 8));
            #pragma unroll
            for (int n = 0; n < 4; n++) {
                bf16x8 bf = *(const bf16x8*)(wswz + ((kt * 16 + wq * 4 + n) * 64 + lane) * 8);
                acc[0][n] = __builtin_amdgcn_mfma_f32_16x16x32_bf16(a0, bf, acc[0][n], 0, 0, 0);
                acc[1][n] = __builtin_amdgcn_mfma_f32_16x16x32_bf16(a1, bf, acc[1][n], 0, 0, 0);
            }
        }

        #pragma unroll
        for (int n = 0; n < 4; n++) {
            float part = 0.f;
            #pragma unroll
            for (int m = 0; m < 2; m++)
                #pragma unroll
                for (int j = 0; j < 4; j++) {
                    int row = m * 16 + rgrp + j;
                    part += fmaxf(acc[m][n][j] + bj[n], 0.f) * escs[ti * 32 + row];
                }
            part += __shfl_xor(part, 16);
            part += __shfl_xor(part, 32);
            colacc[n] += part;
        }
    }

    if (lane < 16) {
        #pragma unroll
        for (int n = 0; n < 4; n++)
            agg1[(long long)l * HID_K + wq * 64 + n * 16 + lane] = colacc[n];
    }
}

// K5: h1[l] = relu((agg1[l]*in_norm)@w_c0 + b_c0)
__global__ __launch_bounds__(256) void k_h1(
    const float* __restrict__ agg1, const float* __restrict__ wc0,
    const float* __restrict__ bc0,
    const int* __restrict__ inF1,
    const int* __restrict__ counters, float* __restrict__ h1)
{
    __shared__ float as[16][HID_K];
    __shared__ float ns[16];

    int nF1 = min(counters[1], F1CAP);
    int base = blockIdx.x * 16;
    if (base >= nF1) return;
    int t = threadIdx.x;

    if (t < 16) {
        int l = base + t;
        ns[t] = (l < nF1) ? rsqrtf((float)max(inF1[l], 1)) : 0.f;
    }
    __syncthreads();

    #pragma unroll
    for (int i = 0; i < 4; i++) {
        int idx = t + i * 256;
        int e = idx >> 6;
        int q = idx & 63;
        int l = base + e;
        float4 v = make_float4(0.f, 0.f, 0.f, 0.f);
        if (l < nF1) v = ((const float4*)(agg1 + (long long)l * HID_K))[q];
        float sc = ns[e];
        v.x *= sc; v.y *= sc; v.z *= sc; v.w *= sc;
        ((float4*)as[e])[q] = v;
    }
    __syncthreads();

    float acc[16];
    #pragma unroll
    for (int e = 0; e < 16; e++) acc[e] = 0.f;

    int j = t;
    for (int k = 0; k < HID_K; k += 4) {
        float w0 = wc0[(k + 0) * HID_K + j];
        float w1 = wc0[(k + 1) * HID_K + j];
        float w2 = wc0[(k + 2) * HID_K + j];
        float w3 = wc0[(k + 3) * HID_K + j];
        #pragma unroll
        for (int e = 0; e < 16; e++) {
            float4 av = *(const float4*)&as[e][k];
            acc[e] = fmaf(av.x, w0, acc[e]);
            acc[e] = fmaf(av.y, w1, acc[e]);
            acc[e] = fmaf(av.z, w2, acc[e]);
            acc[e] = fmaf(av.w, w3, acc[e]);
        }
    }

    float bj = bc0[j];
    #pragma unroll
    for (int e = 0; e < 16; e++) {
        int l = base + e;
        if (l < nF1) h1[(long long)l * HID_K + j] = fmaxf(acc[e] + bj, 0.f);
    }
}

// K6: per agent: gather e0 list, aggregate h1, 2 GEMMs
__global__ __launch_bounds__(256) void k_final(
    const int* __restrict__ e0pack, const int* __restrict__ e0cnt,
    const int* __restrict__ loc, const unsigned int* __restrict__ out_deg,
    const float* __restrict__ h1,
    const float* __restrict__ wc1, const float* __restrict__ bc1,
    const float* __restrict__ wemb, const float* __restrict__ bemb,
    float* __restrict__ out)
{
    __shared__ float a_s[HID_K];
    __shared__ float h2[HID_K];
    __shared__ int   ls[APACK];
    __shared__ float scs[APACK];
    int a = blockIdx.x;
    int t = threadIdx.x;

    int n0 = e0cnt[a];
    int ne = min(n0, APACK);
    if (t < ne) {
        int s = e0pack[a * APACK + t];
        int l = loc[s];
        ls[t] = l;
        scs[t] = (l >= 0) ? rsqrtf((float)max((int)out_deg[s], 1)) : 0.f;
    }
    __syncthreads();

    float acc = 0.f;
    for (int i = 0; i < ne; i++) {
        int l = ls[i];
        if (l >= 0) acc = fmaf(scs[i], h1[(long long)l * HID_K + t], acc);
    }
    a_s[t] = acc * rsqrtf((float)max(n0, 1));
    __syncthreads();

    float h = 0.f;
    for (int k = 0; k < HID_K; k++)
        h = fmaf(a_s[k], wc1[k * HID_K + t], h);
    h2[t] = fmaxf(h + bc1[t], 0.f);
    __syncthreads();

    if (t < EMB_K) {
        float o = bemb[t];
        for (int k = 0; k < HID_K; k++)
            o = fmaf(h2[k], wemb[k * EMB_K + t], o);
        out[a * EMB_K + t] = o;
    }
}

extern "C" void kernel_launch(void* const* d_in, const int* in_sizes, int n_in,
                              void* d_out, int out_size, void* d_ws, size_t ws_size,
                              hipStream_t stream)
{
    const float* x    = (const float*)d_in[0];
    const int*   src  = (const int*)d_in[1];
    const int*   dst  = (const int*)d_in[2];
    const float* wlin = (const float*)d_in[5];
    const float* blin = (const float*)d_in[6];
    const float* wc0  = (const float*)d_in[7];
    const float* bc0  = (const float*)d_in[8];
    const float* wc1  = (const float*)d_in[9];
    const float* bc1  = (const float*)d_in[10];
    const float* wemb = (const float*)d_in[11];
    const float* bemb = (const float*)d_in[12];
    float* out = (float*)d_out;

    char* ws = (char*)d_ws;
    int*            counters  = (int*)(ws + 0);
    int*            inF1      = (int*)(ws + 1024);
    int*            e0cnt     = (int*)(ws + 17408);
    unsigned int*   bitmap    = (unsigned int*)(ws + 17664);
    int*            loc       = (int*)(ws + 65536);
    int*            e0pack    = (int*)(ws + 589824);
    int*            es_bucket = (int*)(ws + 622592);
    unsigned int*   out_deg   = (unsigned int*)(ws + 2195456);
    unsigned short* wswz      = (unsigned short*)(ws + 2719744);
    float*          h1        = (float*)(ws + 2785280);
    float*          agg1      = (float*)(ws + 6979584);
    unsigned int*   partial   = (unsigned int*)(ws + 11173888);

    hipMemsetAsync(ws, 0, ZERO_SPAN, stream);

    k_outdeg_e0<<<G1, 1024, 0, stream>>>(src, dst, partial, bitmap, e0pack, e0cnt);
    k_auxred<<<260, 1024, 0, stream>>>(bitmap, loc, counters,
                                       partial, out_deg, wlin, wswz);
    k_e1_select<<<SELB, 1024, 0, stream>>>(src, dst, loc, bitmap,
                                           inF1, es_bucket);
    k_h0agg<<<F1CAP, 256, 0, stream>>>(x, wswz, blin, es_bucket, out_deg,
                                       inF1, counters, agg1);
    k_h1<<<F1CAP / 16, 256, 0, stream>>>(agg1, wc0, bc0, inF1, counters, h1);
    k_final<<<NAGENT, 256, 0, stream>>>(e0pack, e0cnt, loc, out_deg, h1,
                                        wc1, bc1, wemb, bemb, out);
}

// Round 18
// 107.487 us; speedup vs baseline: 1.7990x; 1.0852x over previous
//
#include <hip/hip_runtime.h>
#include <hip/hip_bf16.h>

#define TOTAL_N   131072
#define NEDGE     4194304
#define NPG       2048
#define IN_DIM_K  128
#define HID_K     256
#define EMB_K     64
#define NAGENT    64

#define F1CAP     4096
#define APACK     128        // per-agent e0 slot cap
#define BCAP      96         // per-F1-node edge bucket cap (mean 32, P(>96)~1e-18)

#define G1        256                 // k_outdeg_e0 blocks
#define EPB1      (NEDGE / G1)        // 16384 edges per block
#define HWORDS    (TOTAL_N / 8)       // 16384 nibble-packed u32 words

#define SELB      256                 // k_e1_select blocks (persistent)
#define EPB       (NEDGE / SELB)      // 16384 edges per block

// ---------------- workspace layout (bytes) ----------------
// zeroed every launch [0, 34048):
//   0        counters  int[256]        ([1]=nF1)
//   1024     inF1      int[F1CAP]      16K
//   17408    e0cnt     int[64]         256B
//   17664    bitmap    u32[4096]       16K
// not zeroed (fully written before read):
//   65536    loc       int[TOTAL_N]    512K
//   589824   e0pack    int[64*APACK]   32K
//   622592   es_bucket int[F1CAP*BCAP] 1.5M
//   2195456  out_deg   u32[TOTAL_N]    512K
//   2719744  wswz      u16[32768]      64K
//   2785280  h1        f32[F1CAP*HID]  4M
//   6979584  agg1      f32[F1CAP*HID]  4M    (rows l<nF1 plain-stored by h0agg)
//   11173888 partial   u32[G1*HWORDS]  16M
// total ~26.7 MB

#define ZERO_SPAN 34048

typedef float f32x4 __attribute__((ext_vector_type(4)));
typedef short bf16x8 __attribute__((ext_vector_type(8)));

__device__ inline unsigned short f2bf(float f) {   // RNE f32->bf16
    unsigned int u = __float_as_uint(f);
    return (unsigned short)((u + 0x7FFFu + ((u >> 16) & 1u)) >> 16);
}

// K1: out-degree nibble histogram + e0 select + F1 bitmap marking
__global__ __launch_bounds__(1024) void k_outdeg_e0(
    const int* __restrict__ src, const int* __restrict__ dst,
    unsigned int* __restrict__ partial,
    unsigned int* __restrict__ bitmap,
    int* __restrict__ e0pack, int* __restrict__ e0cnt)
{
    __shared__ unsigned int hist[HWORDS];   // 64 KB
    int t = threadIdx.x;
    #pragma unroll
    for (int i = 0; i < HWORDS / 1024; i++) hist[t + i * 1024] = 0u;
    __syncthreads();

    int ebase = blockIdx.x * EPB1;
    const int4* s4 = (const int4*)(src + ebase);
    const int4* d4 = (const int4*)(dst + ebase);
    #pragma unroll
    for (int i = 0; i < EPB1 / 4096; i++) {     // 4 iterations
        int4 sv = s4[i * 1024 + t];
        int4 dv = d4[i * 1024 + t];
        int ss[4] = {sv.x, sv.y, sv.z, sv.w};
        int dd[4] = {dv.x, dv.y, dv.z, dv.w};
        #pragma unroll
        for (int j = 0; j < 4; j++) {
            int s = ss[j], d = dd[j];
            atomicAdd(&hist[s >> 3], 1u << ((s & 7) * 4));
            if ((d & (NPG - 1)) == 0) {
                atomicOr(&bitmap[s >> 5], 1u << (s & 31));
                int a = d >> 11;
                int slot = atomicAdd(&e0cnt[a], 1);
                if (slot < APACK) e0pack[a * APACK + slot] = s;
            }
        }
    }
    __syncthreads();
    unsigned int* pout = partial + blockIdx.x * HWORDS;
    #pragma unroll
    for (int i = 0; i < HWORDS / 1024; i++) pout[t + i * 1024] = hist[t + i * 1024];
}

// K2 (merged aux+reduce, 260 blocks x 1024):
//   [0,128) compact | [128,256) out_deg reduce | [256,260) wprep
__global__ __launch_bounds__(1024) void k_auxred(
    const unsigned int* __restrict__ bitmap, int* __restrict__ loc,
    int* __restrict__ counters,
    const unsigned int* __restrict__ partial, unsigned int* __restrict__ out_deg,
    const float* __restrict__ wlin, unsigned short* __restrict__ wswz)
{
    int b = blockIdx.x;
    int t = threadIdx.x;
    if (b < 128) {
        __shared__ int cnt, gbase;
        if (t == 0) cnt = 0;
        __syncthreads();
        int v = b * 1024 + t;
        int f = (bitmap[v >> 5] >> (v & 31)) & 1u;
        int p = -1;
        if (f) p = atomicAdd(&cnt, 1);
        __syncthreads();
        if (t == 0) gbase = cnt ? atomicAdd(&counters[1], cnt) : 0;
        __syncthreads();
        int l = -1;
        if (p >= 0) { int id = gbase + p; if (id < F1CAP) l = id; }
        loc[v] = l;
    } else if (b < 256) {
        __shared__ unsigned int redE[8][128], redO[8][128];   // 8 KB
        int wl = t & 127, gs = t >> 7;
        int w = (b - 128) * 128 + wl;
        unsigned int accE = 0, accO = 0;
        #pragma unroll 8
        for (int i = 0; i < 32; i++) {
            unsigned int v = partial[(gs * 32 + i) * HWORDS + w];
            accE += v & 0x0F0F0F0Fu;
            accO += (v >> 4) & 0x0F0F0F0Fu;
        }
        redE[gs][wl] = accE;
        redO[gs][wl] = accO;
        __syncthreads();
        if (gs == 0) {
            unsigned int sE = 0, sO = 0;
            #pragma unroll
            for (int j = 0; j < 8; j++) { sE += redE[j][wl]; sO += redO[j][wl]; }
            uint4 lo = make_uint4(sE & 255u, sO & 255u, (sE >> 8) & 255u, (sO >> 8) & 255u);
            uint4 hi = make_uint4((sE >> 16) & 255u, (sO >> 16) & 255u, (sE >> 24) & 255u, (sO >> 24) & 255u);
            ((uint4*)(out_deg + 8 * w))[0] = lo;
            ((uint4*)(out_deg + 8 * w))[1] = hi;
        }
    } else {
        int g = (b - 256) * 1024 + t;            // 4096 items
        int lane = g & 63, ct = (g >> 6) & 15, kt = g >> 10;
        int colbase = ct * 16 + (lane & 15);
        int kbase = kt * 32 + (lane >> 4) * 8;
        unsigned short o[8];
        #pragma unroll
        for (int i = 0; i < 8; i++) o[i] = f2bf(wlin[(kbase + i) * HID_K + colbase]);
        *(ushort4*)(wswz + g * 8)     = make_ushort4(o[0], o[1], o[2], o[3]);
        *(ushort4*)(wswz + g * 8 + 4) = make_ushort4(o[4], o[5], o[6], o[7]);
    }
}

// K3: select edges with dst in F1 — direct bucket scatter; slot atomic doubles
// as the inF1 in-degree count.
__global__ __launch_bounds__(1024) void k_e1_select(
    const int* __restrict__ src, const int* __restrict__ dst,
    const int* __restrict__ loc, const unsigned int* __restrict__ bitmap,
    int* __restrict__ inF1, int* __restrict__ es_bucket)
{
    __shared__ unsigned int bm[TOTAL_N / 32];   // 16 KB
    int t = threadIdx.x;
    ((uint4*)bm)[t] = ((const uint4*)bitmap)[t];
    __syncthreads();

    int ebase = blockIdx.x * EPB;
    const int4* d4p = (const int4*)(dst + ebase);
    #pragma unroll
    for (int i = 0; i < EPB / 4096; i++) {      // 4 iterations
        int4 d4 = d4p[i * 1024 + t];
        int eidx = ebase + (i * 1024 + t) * 4;
        int dd[4] = {d4.x, d4.y, d4.z, d4.w};
        #pragma unroll
        for (int j = 0; j < 4; j++) {
            int d = dd[j];
            if ((bm[d >> 5] >> (d & 31)) & 1u) {
                int l = loc[d];
                if (l >= 0) {
                    int slot = atomicAdd(&inF1[l], 1);
                    if (slot < BCAP) es_bucket[l * BCAP + slot] = src[eidx + j];
                }
            }
        }
    }
}

// K4: per-F1-node MFMA edge-GEMM (r14-proven verbatim). Batch gather of all
// tiles barrier-free, then MFMA from LDS, shuffle row-sum, plain store.
__global__ __launch_bounds__(256) void k_h0agg(
    const float* __restrict__ x, const unsigned short* __restrict__ wswz,
    const float* __restrict__ blin, const int* __restrict__ es_bucket,
    const unsigned int* __restrict__ out_deg, const int* __restrict__ inF1,
    const int* __restrict__ counters, float* __restrict__ agg1)
{
    __shared__ unsigned short A[3 * 32][136];   // 25.5 KB: up to 96 bf16 rows
    __shared__ float escs[3 * 32];
    __shared__ int rsrc[3 * 32];

    int nF1 = min(counters[1], F1CAP);
    int l = blockIdx.x;
    if (l >= nF1) return;
    int cnt = min(inF1[l], BCAP);
    int ntile = (cnt + 31) >> 5;            // 0..3
    int t = threadIdx.x;
    int lane = t & 63, wq = t >> 6;
    int cbase = lane & 15, rgrp = (lane >> 4) * 4;

    if (t < 96) {
        int s = (t < cnt) ? es_bucket[l * BCAP + t] : -1;
        rsrc[t] = s;
        escs[t] = (s >= 0) ? rsqrtf((float)max((int)out_deg[s], 1)) : 0.f;
    }
    __syncthreads();

    int nslots = (ntile * 32) * 32;
    for (int idx = t; idx < nslots; idx += 256) {
        int r = idx >> 5, q = idx & 31;
        int s = rsrc[r];
        float4 v = make_float4(0.f, 0.f, 0.f, 0.f);
        if (s >= 0) v = ((const float4*)(x + (long long)s * IN_DIM_K))[q];
        ushort4 h;
        h.x = f2bf(v.x); h.y = f2bf(v.y); h.z = f2bf(v.z); h.w = f2bf(v.w);
        *(ushort4*)&A[r][q * 4] = h;
    }
    __syncthreads();

    float bj[4];
    #pragma unroll
    for (int n = 0; n < 4; n++) bj[n] = blin[wq * 64 + n * 16 + cbase];

    float colacc[4] = {0.f, 0.f, 0.f, 0.f};

    for (int ti = 0; ti < ntile; ti++) {
        f32x4 acc[2][4];
        #pragma unroll
        for (int m = 0; m < 2; m++)
            #pragma unroll
            for (int n = 0; n < 4; n++) acc[m][n] = (f32x4){0.f, 0.f, 0.f, 0.f};

        const unsigned short* Ab = &A[ti * 32][0];
        #pragma unroll
        for (int kt = 0; kt < 4; kt++) {
            bf16x8 a0 = *(const bf16x8*)(Ab + ((lane & 15) * 136 + kt * 32 + (lane >> 4) * 8));
            bf16x8 a1 = *(const bf16x8*)(Ab + (((lane & 15) + 16) * 136 + kt * 32 + (lane >> 4) * 8));
            #pragma unroll
            for (int n = 0; n < 4; n++) {
                bf16x8 bf = *(const bf16x8*)(wswz + ((kt * 16 + wq * 4 + n) * 64 + lane) * 8);
                acc[0][n] = __builtin_amdgcn_mfma_f32_16x16x32_bf16(a0, bf, acc[0][n], 0, 0, 0);
                acc[1][n] = __builtin_amdgcn_mfma_f32_16x16x32_bf16(a1, bf, acc[1][n], 0, 0, 0);
            }
        }

        #pragma unroll
        for (int n = 0; n < 4; n++) {
            float part = 0.f;
            #pragma unroll
            for (int m = 0; m < 2; m++)
                #pragma unroll
                for (int j = 0; j < 4; j++) {
                    int row = m * 16 + rgrp + j;
                    part += fmaxf(acc[m][n][j] + bj[n], 0.f) * escs[ti * 32 + row];
                }
            part += __shfl_xor(part, 16);
            part += __shfl_xor(part, 32);
            colacc[n] += part;
        }
    }

    if (lane < 16) {
        #pragma unroll
        for (int n = 0; n < 4; n++)
            agg1[(long long)l * HID_K + wq * 64 + n * 16 + lane] = colacc[n];
    }
}

// K5 (reshaped): h1 = relu((agg1*in_norm)@wc0 + bc0), column-split 4x.
// Grid: (F1CAP/16) * 4 blocks; block = 16 rows x 64 cols; thread owns 4 outputs.
__global__ __launch_bounds__(256) void k_h1(
    const float* __restrict__ agg1, const float* __restrict__ wc0,
    const float* __restrict__ bc0,
    const int* __restrict__ inF1,
    const int* __restrict__ counters, float* __restrict__ h1)
{
    __shared__ float as[16][HID_K];   // 16 KB
    __shared__ float ns[16];

    int nF1 = min(counters[1], F1CAP);
    int rt = blockIdx.x >> 2;          // row tile
    int cq = blockIdx.x & 3;           // column quarter
    int base = rt * 16;
    if (base >= nF1) return;
    int t = threadIdx.x;

    if (t < 16) {
        int l = base + t;
        ns[t] = (l < nF1) ? rsqrtf((float)max(inF1[l], 1)) : 0.f;
    }
    __syncthreads();

    #pragma unroll
    for (int i = 0; i < 4; i++) {
        int idx = t + i * 256;
        int e = idx >> 6;
        int q = idx & 63;
        int l = base + e;
        float4 v = make_float4(0.f, 0.f, 0.f, 0.f);
        if (l < nF1) v = ((const float4*)(agg1 + (long long)l * HID_K))[q];
        float sc = ns[e];
        v.x *= sc; v.y *= sc; v.z *= sc; v.w *= sc;
        ((float4*)as[e])[q] = v;
    }
    __syncthreads();

    int j = cq * 64 + (t & 63);        // this thread's column
    int rg = (t >> 6) * 4;             // first of this thread's 4 rows
    float acc[4] = {0.f, 0.f, 0.f, 0.f};

    for (int k = 0; k < HID_K; k += 4) {
        float w0 = wc0[(k + 0) * HID_K + j];
        float w1 = wc0[(k + 1) * HID_K + j];
        float w2 = wc0[(k + 2) * HID_K + j];
        float w3 = wc0[(k + 3) * HID_K + j];
        #pragma unroll
        for (int e = 0; e < 4; e++) {
            float4 av = *(const float4*)&as[rg + e][k];
            acc[e] = fmaf(av.x, w0, acc[e]);
            acc[e] = fmaf(av.y, w1, acc[e]);
            acc[e] = fmaf(av.z, w2, acc[e]);
            acc[e] = fmaf(av.w, w3, acc[e]);
        }
    }

    float bj = bc0[j];
    #pragma unroll
    for (int e = 0; e < 4; e++) {
        int l = base + rg + e;
        if (l < nF1) h1[(long long)l * HID_K + j] = fmaxf(acc[e] + bj, 0.f);
    }
}

// K6: per agent: gather e0 list, aggregate h1, 2 GEMMs
__global__ __launch_bounds__(256) void k_final(
    const int* __restrict__ e0pack, const int* __restrict__ e0cnt,
    const int* __restrict__ loc, const unsigned int* __restrict__ out_deg,
    const float* __restrict__ h1,
    const float* __restrict__ wc1, const float* __restrict__ bc1,
    const float* __restrict__ wemb, const float* __restrict__ bemb,
    float* __restrict__ out)
{
    __shared__ float a_s[HID_K];
    __shared__ float h2[HID_K];
    __shared__ int   ls[APACK];
    __shared__ float scs[APACK];
    int a = blockIdx.x;
    int t = threadIdx.x;

    int n0 = e0cnt[a];
    int ne = min(n0, APACK);
    if (t < ne) {
        int s = e0pack[a * APACK + t];
        int l = loc[s];
        ls[t] = l;
        scs[t] = (l >= 0) ? rsqrtf((float)max((int)out_deg[s], 1)) : 0.f;
    }
    __syncthreads();

    float acc = 0.f;
    for (int i = 0; i < ne; i++) {
        int l = ls[i];
        if (l >= 0) acc = fmaf(scs[i], h1[(long long)l * HID_K + t], acc);
    }
    a_s[t] = acc * rsqrtf((float)max(n0, 1));
    __syncthreads();

    float h = 0.f;
    for (int k = 0; k < HID_K; k++)
        h = fmaf(a_s[k], wc1[k * HID_K + t], h);
    h2[t] = fmaxf(h + bc1[t], 0.f);
    __syncthreads();

    if (t < EMB_K) {
        float o = bemb[t];
        for (int k = 0; k < HID_K; k++)
            o = fmaf(h2[k], wemb[k * EMB_K + t], o);
        out[a * EMB_K + t] = o;
    }
}

extern "C" void kernel_launch(void* const* d_in, const int* in_sizes, int n_in,
                              void* d_out, int out_size, void* d_ws, size_t ws_size,
                              hipStream_t stream)
{
    const float* x    = (const float*)d_in[0];
    const int*   src  = (const int*)d_in[1];
    const int*   dst  = (const int*)d_in[2];
    const float* wlin = (const float*)d_in[5];
    const float* blin = (const float*)d_in[6];
    const float* wc0  = (const float*)d_in[7];
    const float* bc0  = (const float*)d_in[8];
    const float* wc1  = (const float*)d_in[9];
    const float* bc1  = (const float*)d_in[10];
    const float* wemb = (const float*)d_in[11];
    const float* bemb = (const float*)d_in[12];
    float* out = (float*)d_out;

    char* ws = (char*)d_ws;
    int*            counters  = (int*)(ws + 0);
    int*            inF1      = (int*)(ws + 1024);
    int*            e0cnt     = (int*)(ws + 17408);
    unsigned int*   bitmap    = (unsigned int*)(ws + 17664);
    int*            loc       = (int*)(ws + 65536);
    int*            e0pack    = (int*)(ws + 589824);
    int*            es_bucket = (int*)(ws + 622592);
    unsigned int*   out_deg   = (unsigned int*)(ws + 2195456);
    unsigned short* wswz      = (unsigned short*)(ws + 2719744);
    float*          h1        = (float*)(ws + 2785280);
    float*          agg1      = (float*)(ws + 6979584);
    unsigned int*   partial   = (unsigned int*)(ws + 11173888);

    hipMemsetAsync(ws, 0, ZERO_SPAN, stream);

    k_outdeg_e0<<<G1, 1024, 0, stream>>>(src, dst, partial, bitmap, e0pack, e0cnt);
    k_auxred<<<260, 1024, 0, stream>>>(bitmap, loc, counters,
                                       partial, out_deg, wlin, wswz);
    k_e1_select<<<SELB, 1024, 0, stream>>>(src, dst, loc, bitmap,
                                           inF1, es_bucket);
    k_h0agg<<<F1CAP, 256, 0, stream>>>(x, wswz, blin, es_bucket, out_deg,
                                       inF1, counters, agg1);
    k_h1<<<(F1CAP / 16) * 4, 256, 0, stream>>>(agg1, wc0, bc0, inF1,
                                               counters, h1);
    k_final<<<NAGENT, 256, 0, stream>>>(e0pack, e0cnt, loc, out_deg, h1,
                                        wc1, bc1, wemb, bemb, out);
}